// Round 4
// baseline (341.164 us; speedup 1.0000x reference)
//
#include <hip/hip_runtime.h>
#include <hip/hip_bf16.h>

typedef unsigned short u16;
typedef unsigned int u32;
typedef __attribute__((ext_vector_type(8))) short short8;
typedef __attribute__((ext_vector_type(4))) float float4v;
typedef __attribute__((ext_vector_type(4))) unsigned short u16x4;

#define T_DIM 2048
#define D_DIM 2048
#define N_DIM 11264
#define BD    5632
#define KE    256   // extra K from LoRA fold-in (L*R = 16*16)

__device__ __forceinline__ u16 f2bf(float f) {
    union { float f; u32 u; } v; v.f = f;
    u32 u = v.u;
    return (u16)((u + 0x7fffu + ((u >> 16) & 1u)) >> 16);  // RNE, inputs finite
}

__device__ __forceinline__ void gld16(const u16* g, u16* l) {
    // async global->LDS, 16B per lane; LDS dest = wave-uniform base + lane*16
    __builtin_amdgcn_global_load_lds((const __attribute__((address_space(1))) void*)g,
                                     (__attribute__((address_space(3))) void*)l, 16, 0, 0);
}

// coalesced grid-stride f32 -> bf16 convert: per instruction, lane-consecutive
// float4 loads (1 KB/wave) and u16x4 stores (512 B/wave); 8 loads in flight.
__device__ __forceinline__ void cvt8(const float* __restrict__ src,
                                     u16* __restrict__ dst,
                                     int gid, int stride) {
    float4 v[8];
#pragma unroll
    for (int k = 0; k < 8; ++k)
        v[k] = ((const float4*)src)[(size_t)gid + (size_t)k * stride];
#pragma unroll
    for (int k = 0; k < 8; ++k) {
        u16x4 o;
        o[0] = f2bf(v[k].x); o[1] = f2bf(v[k].y);
        o[2] = f2bf(v[k].z); o[3] = f2bf(v[k].w);
        *(u16x4*)(dst + ((size_t)gid + (size_t)k * stride) * 4) = o;
    }
}

// ---------------------------------------------------------------------------
// Prep kernel (f32 inputs). Phase interleave (xa latency-bound blocks share
// CUs with BW-bound W-convert blocks):
//  bid [0,4096):     even -> xa token bid/2; odd -> W-convert block bid/2
//  bid [4096,4864):  W-convert blocks 2048..2815
//  bid [4864,5376):  X-convert blocks 0..511
//  bid [5376,8192):  B-transpose blocks 0..2815
// ---------------------------------------------------------------------------
__global__ __launch_bounds__(256) void prep_kernel(
    const float* __restrict__ Xf, const float* __restrict__ Wf,
    const float* __restrict__ Af, const float* __restrict__ Bf,
    const int* __restrict__ widx,
    u16* __restrict__ Wb, u16* __restrict__ Xb,
    u16* __restrict__ XH0, u16* __restrict__ XH1, u16* __restrict__ BT)
{
    const int bid = blockIdx.x;
    const int tid = threadIdx.x;

    __shared__ float lx[D_DIM];          // staged x row (8 KB)
    __shared__ float red[4][8][4];
    __shared__ float xa[32];
    __shared__ u16 tile[32][33];

    int phase, pb;
    if (bid < 4096)      { phase = (bid & 1);      pb = bid >> 1; }
    else if (bid < 4864) { phase = 1;              pb = 2048 + (bid - 4096); }
    else if (bid < 5376) { phase = 2;              pb = bid - 4864; }
    else                 { phase = 3;              pb = bid - 5376; }

    if (phase == 0) {
        // ---- xa for token t ----
        const int t = pb;
        const int l = widx[t];
        const float4* xr = (const float4*)(Xf + (size_t)t * D_DIM);
        ((float4*)lx)[tid]       = xr[tid];
        ((float4*)lx)[tid + 256] = xr[tid + 256];
        __syncthreads();

        const int wave = tid >> 6, lane = tid & 63;
        const int rowg = lane >> 3, chunk = lane & 7;
        // wave-load: 8 consecutive rows x 128 B, fully coalesced 1 KB
        const float* abase = Af + (size_t)l * (D_DIM * 32) + chunk * 4;
        float accx = 0.f, accy = 0.f, accz = 0.f, accw = 0.f;
#pragma unroll 8
        for (int i = 0; i < 64; ++i) {
            const int row = wave * 512 + i * 8 + rowg;
            const float4 av = *(const float4*)(abase + (size_t)row * 32);
            const float xf = lx[row];
            accx += xf * av.x; accy += xf * av.y;
            accz += xf * av.z; accw += xf * av.w;
        }
        // reduce across the 8 rowgroups (xor 8/16/32)
#pragma unroll
        for (int off = 8; off <= 32; off <<= 1) {
            accx += __shfl_xor(accx, off);
            accy += __shfl_xor(accy, off);
            accz += __shfl_xor(accz, off);
            accw += __shfl_xor(accw, off);
        }
        if (rowg == 0) {
            red[wave][chunk][0] = accx; red[wave][chunk][1] = accy;
            red[wave][chunk][2] = accz; red[wave][chunk][3] = accw;
        }
        __syncthreads();
        if (tid < 32) {
            const int c = tid >> 2, j = tid & 3;
            xa[c * 4 + j] = red[0][c][j] + red[1][c][j] + red[2][c][j] + red[3][c][j];
        }
        __syncthreads();
        // scatter: k = tid; xahat_h[t, l'*16+r] = (l'==l) ? xa[h*16+r] : 0
        const int k = tid, kl = k >> 4, r = k & 15;
        const bool hit = (kl == l);
        XH0[(size_t)t * KE + k] = hit ? f2bf(xa[r])      : (u16)0;
        XH1[(size_t)t * KE + k] = hit ? f2bf(xa[16 + r]) : (u16)0;
    } else if (phase == 1) {
        // ---- W convert: 23.07M floats, 2816 blocks x 256 thr x 8 float4 ----
        cvt8(Wf, Wb, pb * 256 + tid, 720896);
    } else if (phase == 2) {
        // ---- X convert: 4.19M floats, 512 blocks ----
        cvt8(Xf, Xb, pb * 256 + tid, 131072);
    } else {
        // ---- 32x32 tiled transpose + convert: BT[n,k] = bf16(B[k,n]) ----
        const int nb = pb >> 3;   // 0..351
        const int kb = pb & 7;    // 0..7
        const int tx = tid & 31, ty = tid >> 5;
        const int n = nb * 32 + tx;
#pragma unroll
        for (int i = 0; i < 4; ++i) {
            const int kk = kb * 32 + ty + i * 8;
            tile[ty + i * 8][tx] = f2bf(Bf[(size_t)kk * N_DIM + n]);
        }
        __syncthreads();
        const int k2 = kb * 32 + tx;
#pragma unroll
        for (int i = 0; i < 4; ++i) {
            const int n2 = nb * 32 + ty + i * 8;
            BT[(size_t)n2 * KE + k2] = tile[tx][ty + i * 8];
        }
    }
}

// ---------------------------------------------------------------------------
// Main GEMM: out[m,n] = sum_k xb[m,k] wb[n,k]  (K=2048, bf16)
//                     + sum_k xahat_h[m,k] BT[n,k]  (K=256, h by n-half)
// 128x128 tile, 4 waves (2x2), each wave 4x4 frags of 16x16x32 bf16 MFMA.
// BK=32. global_load_lds staging with XOR-swizzled LDS chunk layout
// (zero bank conflicts, verified R3). Block order m-fastest: a co-resident
// cohort spans ~32 n-tiles x 16 m-tiles -> W+X working set ~24 MB < 32 MB L2.
// Output f32.
// ---------------------------------------------------------------------------
__global__ __launch_bounds__(256, 2) void gemm_kernel(
    const u16* __restrict__ X, const u16* __restrict__ W,
    const u16* __restrict__ XH0, const u16* __restrict__ XH1,
    const u16* __restrict__ BT, float* __restrict__ OUT)
{
    __shared__ __align__(16) u16 lsA[128 * 32];
    __shared__ __align__(16) u16 lsB[128 * 32];

    const int tid  = threadIdx.x;
    const int lane = tid & 63;
    const int wave = tid >> 6;
    const int wm = wave >> 1, wn = wave & 1;
    const int q = lane >> 4, c16 = lane & 15;
    const int bm = blockIdx.x, bn = blockIdx.y;   // m-fastest dispatch order
    const int m0 = bm * 128, n0 = bn * 128;

    // staging: lane's LDS chunk = lane (within instr); global chunk = involution
    const int gchunk = lane ^ ((lane >> 3) & 7);
    const int srow = gchunk >> 2;  // row within 16-row instruction span
    const int skq  = gchunk & 3;   // 16B chunk within 64B row

    // fragment read: local chunk for (row=c16, kchunk=q) within its group
    const int gl = (c16 << 2) | q;
    const int cl = gl ^ ((gl >> 3) & 7);

    u16* ldsA0 = lsA + wave * 1024;  // 16 rows x 32 k = 1024B per gld16
    u16* ldsA1 = ldsA0 + 512;
    u16* ldsB0 = lsB + wave * 1024;
    u16* ldsB1 = ldsB0 + 512;

    const size_t arow = (size_t)(m0 + wave * 32 + srow);
    const size_t brow = (size_t)(n0 + wave * 32 + srow);
    const int aoff = skq * 8;

    const u16* pa0 = X + arow * D_DIM + aoff;
    const u16* pa1 = pa0 + 16 * D_DIM;
    const u16* pb0 = W + brow * D_DIM + aoff;
    const u16* pb1 = pb0 + 16 * D_DIM;

    float4v acc[4][4] = {};

    auto mma_step = [&]() {
        short8 af[4], bf[4];
#pragma unroll
        for (int i = 0; i < 4; ++i)
            af[i] = *(const short8*)(lsA + (((wm * 4 + i) * 64 + cl) << 3));
#pragma unroll
        for (int j = 0; j < 4; ++j)
            bf[j] = *(const short8*)(lsB + (((wn * 4 + j) * 64 + cl) << 3));
#pragma unroll
        for (int i = 0; i < 4; ++i)
#pragma unroll
            for (int j = 0; j < 4; ++j)
                acc[i][j] = __builtin_amdgcn_mfma_f32_16x16x32_bf16(af[i], bf[j], acc[i][j], 0, 0, 0);
    };

    for (int kt = 0; kt < 64; ++kt) {
        const int k0 = kt * 32;
        __syncthreads();
        gld16(pa0 + k0, ldsA0);
        gld16(pa1 + k0, ldsA1);
        gld16(pb0 + k0, ldsB0);
        gld16(pb1 + k0, ldsB1);
        __syncthreads();
        mma_step();
    }

    // LoRA extra-K: 8 iterations, half selected by n-block (tiles never straddle)
    const u16* xah = (n0 < BD) ? XH0 : XH1;
    const u16* ea0 = xah + arow * KE + aoff;
    const u16* ea1 = ea0 + 16 * KE;
    const u16* eb0 = BT + brow * KE + aoff;
    const u16* eb1 = eb0 + 16 * KE;
    for (int kt = 0; kt < 8; ++kt) {
        const int k0 = kt * 32;
        __syncthreads();
        gld16(ea0 + k0, ldsA0);
        gld16(ea1 + k0, ldsA1);
        gld16(eb0 + k0, ldsB0);
        gld16(eb1 + k0, ldsB1);
        __syncthreads();
        mma_step();
    }

    // epilogue: C/D layout col = lane&15, row = (lane>>4)*4 + reg
    const int crow = m0 + wm * 64 + q * 4;
    const int ccol = n0 + wn * 64 + c16;
#pragma unroll
    for (int i = 0; i < 4; ++i)
#pragma unroll
        for (int j = 0; j < 4; ++j) {
#pragma unroll
            for (int r = 0; r < 4; ++r)
                OUT[(size_t)(crow + i * 16 + r) * N_DIM + (ccol + j * 16)] = acc[i][j][r];
        }
}

extern "C" void kernel_launch(void* const* d_in, const int* in_sizes, int n_in,
                              void* d_out, int out_size, void* d_ws, size_t ws_size,
                              hipStream_t stream) {
    const float* Xf  = (const float*)d_in[0];   // (2048, 2048) f32
    const float* Wf  = (const float*)d_in[1];   // (11264, 2048) f32
    const float* Af  = (const float*)d_in[2];   // (16, 2048, 32) f32
    const float* Bf  = (const float*)d_in[3];   // (16, 16, 11264) f32
    const int* widx  = (const int*)d_in[4];     // (2048,) int32 (JAX x64 off)
    float* OUT = (float*)d_out;                 // (2048, 11264) f32

    u16* Wb  = (u16*)d_ws;                            // 11264x2048 bf16 (46.1 MB)
    u16* Xb  = Wb + (size_t)N_DIM * D_DIM;            // 2048x2048 bf16 (8.4 MB)
    u16* XH0 = Xb + (size_t)T_DIM * D_DIM;            // 2048x256 bf16 (1 MB)
    u16* XH1 = XH0 + (size_t)T_DIM * KE;              // 2048x256 bf16 (1 MB)
    u16* BT  = XH1 + (size_t)T_DIM * KE;              // 11264x256 bf16 (5.5 MB)

    prep_kernel<<<dim3(8192), dim3(256), 0, stream>>>(Xf, Wf, Af, Bf, widx,
                                                      Wb, Xb, XH0, XH1, BT);
    gemm_kernel<<<dim3(T_DIM / 128, N_DIM / 128), dim3(256), 0, stream>>>(
        Xb, Wb, XH0, XH1, BT, OUT);
}